// Round 1
// baseline (1004.939 us; speedup 1.0000x reference)
//
#include <hip/hip_runtime.h>

#define DEV __device__ __forceinline__

typedef __bf16 bf16x8 __attribute__((ext_vector_type(8)));
typedef float  f32x4  __attribute__((ext_vector_type(4)));

#define MFMA_BF16(A,B,C) __builtin_amdgcn_mfma_f32_16x16x32_bf16((A),(B),(C),0,0,0)

DEV unsigned short f2bf(float f) {          // fp32 -> bf16, round-nearest-even (no NaN in our data)
  unsigned int u = __builtin_bit_cast(unsigned int, f);
  u += 0x7fffu + ((u >> 16) & 1u);
  return (unsigned short)(u >> 16);
}
DEV float bf2f(unsigned short s) {
  unsigned int u = ((unsigned int)s) << 16;
  return __builtin_bit_cast(float, u);
}

// ---- problem sizes ----
constexpr int Bn  = 4096;
constexpr int Nr  = 90;     // graph nodes
constexpr int Tt  = 195;    // time dim
constexpr int Hh  = 20;     // GCN hidden
constexpr int NP  = 96;     // padded N (6*16)
constexpr int KT  = 224;    // padded T (7*32)
constexpr int XS  = 232;    // LDS x row stride in bf16 (29 16B-banks: odd -> conflict-free frag reads)
constexpr int AS  = 104;    // LDS adj/xwbt row stride in bf16 (13 16B-banks: odd)
constexpr int D1P = 1824;   // padded flat dim (57*32), real 1800
constexpr int C1  = 512;
constexpr int C2  = 256;

// =====================================================================
// prep: bf16-transposed weights (zero-padded K) + gc1 hi/lo split (B-layout [h][t])
// =====================================================================
__global__ __launch_bounds__(256) void k_prep(
    const float* __restrict__ gc1,   // [195][20]
    const float* __restrict__ l1w,   // [1800][512]
    const float* __restrict__ l2w,   // [512][256]
    unsigned short* __restrict__ g1hi, unsigned short* __restrict__ g1lo, // [32][224]
    unsigned short* __restrict__ wT1,  // [512][1824]
    unsigned short* __restrict__ wT2)  // [256][512]
{
  int tid = blockIdx.x * 256 + threadIdx.x;
  int stride = gridDim.x * 256;
  for (int i = tid; i < 32*KT; i += stride) {
    int h = i / KT, t = i - h*KT;
    float f = (h < Hh && t < Tt) ? gc1[t*Hh + h] : 0.f;
    unsigned short hi = f2bf(f);
    g1hi[i] = hi;
    g1lo[i] = f2bf(f - bf2f(hi));
  }
  for (int i = tid; i < C1*D1P; i += stride) {
    int c = i / D1P, k = i - c*D1P;
    wT1[i] = f2bf(k < 1800 ? l1w[(size_t)k*C1 + c] : 0.f);
  }
  for (int i = tid; i < C2*C1; i += stride) {
    int c = i / C1, k = i - c*C1;
    wT2[i] = f2bf(l2w[(size_t)k*C2 + c]);
  }
}

// =====================================================================
// stage1: one block per sample. corr (split-bf16 MFMA, ~fp32 accurate),
// then GCN: h2 = adj@((adj@(x@W1))@W2), written as bf16 flat rows (padded 1824).
// =====================================================================
__global__ __launch_bounds__(256) void k_stage1(
    const float* __restrict__ x,
    const unsigned short* __restrict__ g1hi,
    const unsigned short* __restrict__ g1lo,
    const float* __restrict__ gc2,      // [20][20] fp32, read via uniform s_loads
    unsigned short* __restrict__ flatB) // [4096][1824] bf16
{
  __shared__ unsigned short xhi[NP][XS];
  __shared__ unsigned short xlo[NP][XS];
  __shared__ unsigned short adjh[NP][AS];
  __shared__ unsigned short adjl[NP][AS];
  __shared__ unsigned short xwbt[32][AS];   // xw^T  [h][m] (B-operand layout)
  __shared__ unsigned short hgbt[32][AS];   // h1g^T [h][m]
  __shared__ float shout[NP][21];           // h1 then h2 (fp32)
  __shared__ float smean[NP];
  __shared__ float sdinv[NP];
  __shared__ float scov[NP];

  const int tid = threadIdx.x;
  const int b   = blockIdx.x;
  const int w   = tid >> 6;
  const int l   = tid & 63;
  const int wr  = w >> 1;
  const int wc  = w & 1;
  const int fm  = l & 15;          // A-frag row / B-frag col
  const int fk  = (l >> 4) * 8;    // frag k-offset

  // ---- zero LDS (pads must be 0 so MFMA pad lanes contribute 0, never NaN) ----
  {
    int4 z; z.x = z.y = z.z = z.w = 0;
    int4* p1 = (int4*)(&xhi[0][0]);
    int4* p2 = (int4*)(&xlo[0][0]);
    for (int i = tid; i < NP*XS/8; i += 256) { p1[i] = z; p2[i] = z; }
    int4* p3 = (int4*)(&adjh[0][0]);
    int4* p4 = (int4*)(&adjl[0][0]);
    for (int i = tid; i < NP*AS/8; i += 256) { p3[i] = z; p4[i] = z; }
    int4* p5 = (int4*)(&xwbt[0][0]);
    int4* p6 = (int4*)(&hgbt[0][0]);
    for (int i = tid; i < 32*AS/8; i += 256) { p5[i] = z; p6[i] = z; }
  }
  __syncthreads();

  // ---- load x, split into bf16 hi + lo ----
  const float* xb = x + (size_t)b * (Nr*Tt);
  for (int i = tid; i < Nr*Tt; i += 256) {
    int r = i / Tt;
    int t = i - r*Tt;
    float f = xb[i];
    unsigned short hi = f2bf(f);
    xhi[r][t] = hi;
    xlo[r][t] = f2bf(f - bf2f(hi));
  }
  __syncthreads();

  // ---- row means (hi+lo reconstructs x to ~2^-17) ----
  if (tid < Nr) {
    const ushort4* ph = (const ushort4*)(&xhi[tid][0]);
    const ushort4* pl = (const ushort4*)(&xlo[tid][0]);
    float s = 0.f;
    for (int q = 0; q < 49; ++q) {   // covers t 0..195 (t=195 is zero pad)
      ushort4 h = ph[q], lo = pl[q];
      s += bf2f(h.x) + bf2f(h.y) + bf2f(h.z) + bf2f(h.w);
      s += bf2f(lo.x) + bf2f(lo.y) + bf2f(lo.z) + bf2f(lo.w);
    }
    smean[tid] = s * (1.f/195.f);
  }
  __syncthreads();

  // ---- cov = x @ x^T via split-bf16 MFMA. wave(wr,wc) owns 48x48 quadrant (3x3 tiles) ----
  f32x4 cacc[3][3];
  #pragma unroll
  for (int i = 0; i < 3; ++i)
    #pragma unroll
    for (int j = 0; j < 3; ++j) cacc[i][j] = f32x4{0.f,0.f,0.f,0.f};

  for (int ks = 0; ks < 7; ++ks) {
    const int k0 = ks*32 + fk;
    bf16x8 ah[3], al[3], bh[3], bl[3];
    #pragma unroll
    for (int t2 = 0; t2 < 3; ++t2) {
      ah[t2] = *(const bf16x8*)(&xhi[wr*48 + t2*16 + fm][k0]);
      al[t2] = *(const bf16x8*)(&xlo[wr*48 + t2*16 + fm][k0]);
      bh[t2] = *(const bf16x8*)(&xhi[wc*48 + t2*16 + fm][k0]);
      bl[t2] = *(const bf16x8*)(&xlo[wc*48 + t2*16 + fm][k0]);
    }
    #pragma unroll
    for (int ti = 0; ti < 3; ++ti)
      #pragma unroll
      for (int tj = 0; tj < 3; ++tj) {
        cacc[ti][tj] = MFMA_BF16(ah[ti], bh[tj], cacc[ti][tj]);
        cacc[ti][tj] = MFMA_BF16(al[ti], bh[tj], cacc[ti][tj]);
        cacc[ti][tj] = MFMA_BF16(ah[ti], bl[tj], cacc[ti][tj]);
      }
  }

  // raw diag -> scov (C layout: row=(l>>4)*4+reg, col=l&15; diag when equal)
  if (wr == wc) {
    #pragma unroll
    for (int t2 = 0; t2 < 3; ++t2)
      #pragma unroll
      for (int reg = 0; reg < 4; ++reg) {
        int rloc = (l >> 4)*4 + reg;
        if (rloc == fm) scov[wr*48 + t2*16 + rloc] = cacc[t2][t2][reg];
      }
  }
  __syncthreads();

  if (tid < Nr) {
    float m = smean[tid];
    sdinv[tid] = rsqrtf(fmaxf(scov[tid] - 195.f*m*m, 1e-20f));
  }
  __syncthreads();

  // ---- corr = clip((cov - T*mu_i*mu_j) * dinv_i * dinv_j) -> adj bf16 hi/lo ----
  #pragma unroll
  for (int ti = 0; ti < 3; ++ti) {
    #pragma unroll
    for (int tj = 0; tj < 3; ++tj) {
      int ccol = wc*48 + tj*16 + fm;
      if (ccol < Nr) {
        float mc = smean[ccol], dc = sdinv[ccol];
        #pragma unroll
        for (int reg = 0; reg < 4; ++reg) {
          int rr = wr*48 + ti*16 + (l>>4)*4 + reg;
          if (rr < Nr) {
            float v = (cacc[ti][tj][reg] - 195.f*smean[rr]*mc) * (sdinv[rr]*dc);
            v = fminf(1.f, fmaxf(-1.f, v));
            unsigned short hi = f2bf(v);
            adjh[rr][ccol] = hi;
            adjl[rr][ccol] = f2bf(v - bf2f(hi));
          }
        }
      }
    }
  }
  __syncthreads();

  // ---- xw = x @ gc1 (3-term split), write transposed bf16 xwbt[h][m] ----
  for (int mt = w; mt < 6; mt += 4) {
    f32x4 xacc[2];
    xacc[0] = f32x4{0.f,0.f,0.f,0.f};
    xacc[1] = f32x4{0.f,0.f,0.f,0.f};
    for (int ks = 0; ks < 7; ++ks) {
      const int k0 = ks*32 + fk;
      bf16x8 ah = *(const bf16x8*)(&xhi[mt*16 + fm][k0]);
      bf16x8 al = *(const bf16x8*)(&xlo[mt*16 + fm][k0]);
      #pragma unroll
      for (int nt = 0; nt < 2; ++nt) {
        bf16x8 bh = *(const bf16x8*)(g1hi + (size_t)(nt*16 + fm)*KT + k0);
        bf16x8 bl = *(const bf16x8*)(g1lo + (size_t)(nt*16 + fm)*KT + k0);
        xacc[nt] = MFMA_BF16(ah, bh, xacc[nt]);
        xacc[nt] = MFMA_BF16(al, bh, xacc[nt]);
        xacc[nt] = MFMA_BF16(ah, bl, xacc[nt]);
      }
    }
    #pragma unroll
    for (int nt = 0; nt < 2; ++nt) {
      int hcol = nt*16 + fm;
      if (hcol < Hh) {
        #pragma unroll
        for (int reg = 0; reg < 4; ++reg) {
          int rr = mt*16 + (l>>4)*4 + reg;
          if (rr < Nr) xwbt[hcol][rr] = f2bf(xacc[nt][reg]);
        }
      }
    }
  }
  __syncthreads();

  // ---- h1 = adj @ xw (adj split hi/lo) -> shout fp32 ----
  for (int mt = w; mt < 6; mt += 4) {
    f32x4 dacc[2];
    dacc[0] = f32x4{0.f,0.f,0.f,0.f};
    dacc[1] = f32x4{0.f,0.f,0.f,0.f};
    #pragma unroll
    for (int ks = 0; ks < 3; ++ks) {
      const int k0 = ks*32 + fk;
      bf16x8 ah = *(const bf16x8*)(&adjh[mt*16 + fm][k0]);
      bf16x8 al = *(const bf16x8*)(&adjl[mt*16 + fm][k0]);
      #pragma unroll
      for (int nt = 0; nt < 2; ++nt) {
        bf16x8 bb = *(const bf16x8*)(&xwbt[nt*16 + fm][k0]);
        dacc[nt] = MFMA_BF16(ah, bb, dacc[nt]);
        dacc[nt] = MFMA_BF16(al, bb, dacc[nt]);
      }
    }
    #pragma unroll
    for (int nt = 0; nt < 2; ++nt) {
      int hcol = nt*16 + fm;
      if (hcol < Hh) {
        #pragma unroll
        for (int reg = 0; reg < 4; ++reg) {
          int rr = mt*16 + (l>>4)*4 + reg;
          if (rr < Nr) shout[rr][hcol] = dacc[nt][reg];
        }
      }
    }
  }
  __syncthreads();

  // ---- h1g = h1 @ gc2 (fp32, gc2 via wave-uniform s_loads) -> hgbt bf16 ----
  {
    int n = tid & 127;
    int hh2 = __builtin_amdgcn_readfirstlane(tid >> 7);  // 0 for waves 0/1, 1 for 2/3
    int h0 = hh2 * 10;
    if (n < Nr) {
      float acc2[10];
      #pragma unroll
      for (int j = 0; j < 10; ++j) acc2[j] = 0.f;
      for (int k = 0; k < Hh; ++k) {
        float v = shout[n][k];
        #pragma unroll
        for (int j = 0; j < 10; ++j) acc2[j] += v * gc2[k*Hh + h0 + j];
      }
      #pragma unroll
      for (int j = 0; j < 10; ++j) hgbt[h0 + j][n] = f2bf(acc2[j]);
    }
  }
  __syncthreads();

  // ---- h2 = adj @ h1g -> shout (overwrite) ----
  for (int mt = w; mt < 6; mt += 4) {
    f32x4 facc[2];
    facc[0] = f32x4{0.f,0.f,0.f,0.f};
    facc[1] = f32x4{0.f,0.f,0.f,0.f};
    #pragma unroll
    for (int ks = 0; ks < 3; ++ks) {
      const int k0 = ks*32 + fk;
      bf16x8 ah = *(const bf16x8*)(&adjh[mt*16 + fm][k0]);
      bf16x8 al = *(const bf16x8*)(&adjl[mt*16 + fm][k0]);
      #pragma unroll
      for (int nt = 0; nt < 2; ++nt) {
        bf16x8 bb = *(const bf16x8*)(&hgbt[nt*16 + fm][k0]);
        facc[nt] = MFMA_BF16(ah, bb, facc[nt]);
        facc[nt] = MFMA_BF16(al, bb, facc[nt]);
      }
    }
    #pragma unroll
    for (int nt = 0; nt < 2; ++nt) {
      int hcol = nt*16 + fm;
      if (hcol < Hh) {
        #pragma unroll
        for (int reg = 0; reg < 4; ++reg) {
          int rr = mt*16 + (l>>4)*4 + reg;
          if (rr < Nr) shout[rr][hcol] = facc[nt][reg];
        }
      }
    }
  }
  __syncthreads();

  // ---- store flat row as bf16, zero-padded to 1824 ----
  {
    const size_t base = (size_t)b * D1P;
    for (int i = tid; i < D1P; i += 256) {
      unsigned short v = 0;
      if (i < 1800) {
        int r = i / Hh;
        int c = i - r*Hh;
        v = f2bf(shout[r][c]);
      }
      flatB[base + i] = v;
    }
  }
}

// =====================================================================
// GEMM: C[M,Ncols](f32) = A[M,K](bf16) @ WT[Ncols,K](bf16)^T + bias.
// 64x64 block, 4 waves (32x32 each), direct-global fragments (no LDS).
// =====================================================================
__global__ __launch_bounds__(256) void k_gemm_bt(
    const unsigned short* __restrict__ A,
    const unsigned short* __restrict__ WT,
    const float* __restrict__ bias,
    float* __restrict__ C,
    int lda, int ldw, int ldc, int ksteps)
{
  const int tid = threadIdx.x;
  const int w = tid >> 6, l = tid & 63;
  const int wr = w >> 1, wc = w & 1;
  const int fm = l & 15, fk = (l >> 4) * 8;
  const int m0 = blockIdx.x * 64;
  const int n0 = blockIdx.y * 64;

  const unsigned short* pa0 = A  + (size_t)(m0 + wr*32 + fm) * lda + fk;
  const unsigned short* pa1 = pa0 + (size_t)16 * lda;
  const unsigned short* pb0 = WT + (size_t)(n0 + wc*32 + fm) * ldw + fk;
  const unsigned short* pb1 = pb0 + (size_t)16 * ldw;

  f32x4 acc00 = f32x4{0.f,0.f,0.f,0.f};
  f32x4 acc01 = acc00, acc10 = acc00, acc11 = acc00;

  for (int ks = 0; ks < ksteps; ++ks) {
    const int o = ks * 32;
    bf16x8 a0 = *(const bf16x8*)(pa0 + o);
    bf16x8 a1 = *(const bf16x8*)(pa1 + o);
    bf16x8 b0 = *(const bf16x8*)(pb0 + o);
    bf16x8 b1 = *(const bf16x8*)(pb1 + o);
    acc00 = MFMA_BF16(a0, b0, acc00);
    acc01 = MFMA_BF16(a0, b1, acc01);
    acc10 = MFMA_BF16(a1, b0, acc10);
    acc11 = MFMA_BF16(a1, b1, acc11);
  }

  const int rb = m0 + wr*32 + (l >> 4)*4;
  const int cb = n0 + wc*32 + fm;
  const float bv0 = bias[cb];
  const float bv1 = bias[cb + 16];
  #pragma unroll
  for (int reg = 0; reg < 4; ++reg) {
    C[(size_t)(rb + reg)*ldc + cb]           = acc00[reg] + bv0;
    C[(size_t)(rb + reg)*ldc + cb + 16]      = acc01[reg] + bv1;
    C[(size_t)(rb + 16 + reg)*ldc + cb]      = acc10[reg] + bv0;
    C[(size_t)(rb + 16 + reg)*ldc + cb + 16] = acc11[reg] + bv1;
  }
}

// =====================================================================
// BatchNorm column stats -> fused affine a*y + c
// =====================================================================
__global__ __launch_bounds__(256) void k_bnstats(
    const float* __restrict__ Y, int C,
    const float* __restrict__ gamma, const float* __restrict__ beta,
    float* __restrict__ a, float* __restrict__ cc)
{
  __shared__ float ss[16][17], sq[16][17];
  int cl = threadIdx.x & 15, rc = threadIdx.x >> 4;
  int c = blockIdx.x*16 + cl;
  float s = 0.f, s2 = 0.f;
  for (int r = rc; r < Bn; r += 16) {
    float v = Y[(size_t)r*C + c];
    s += v; s2 += v*v;
  }
  ss[rc][cl] = s; sq[rc][cl] = s2;
  __syncthreads();
  if (rc == 0) {
    float S = 0.f, S2 = 0.f;
    #pragma unroll
    for (int t = 0; t < 16; ++t) { S += ss[t][cl]; S2 += sq[t][cl]; }
    float m   = S  * (1.f/Bn);
    float var = S2 * (1.f/Bn) - m*m;
    float av  = gamma[c] * rsqrtf(var + 1e-5f);
    a[c]  = av;
    cc[c] = beta[c] - av*m;
  }
}

__global__ __launch_bounds__(256) void k_bnapply(
    const float* __restrict__ Y, const float* __restrict__ a,
    const float* __restrict__ cc, unsigned short* __restrict__ Z)
{
  const int total = Bn * C1;
  for (int i = blockIdx.x*256 + threadIdx.x; i < total; i += 2048*256) {
    int col = i & (C1-1);
    Z[i] = f2bf(a[col]*Y[i] + cc[col]);
  }
}

// =====================================================================
// final: logits = (a2*Y2+c2) @ l3_w + l3_b, softmax over 2 classes
// block = 64 rows x 4 k-chunks
// =====================================================================
__global__ __launch_bounds__(256) void k_final(
    const float* __restrict__ Y2,
    const float* __restrict__ a2, const float* __restrict__ c2,
    const float* __restrict__ l3w, const float* __restrict__ l3b,
    float* __restrict__ out)
{
  __shared__ float p0[4][64], p1[4][64];
  int rl = threadIdx.x & 63, kc = threadIdx.x >> 6;
  int r = blockIdx.x*64 + rl;
  float s0 = 0.f, s1 = 0.f;
  for (int k = kc*64; k < kc*64 + 64; ++k) {
    float z = a2[k]*Y2[(size_t)r*C2 + k] + c2[k];
    s0 += z * l3w[2*k];
    s1 += z * l3w[2*k + 1];
  }
  p0[kc][rl] = s0; p1[kc][rl] = s1;
  __syncthreads();
  if (kc == 0) {
    float l0 = p0[0][rl] + p0[1][rl] + p0[2][rl] + p0[3][rl] + l3b[0];
    float l1 = p1[0][rl] + p1[1][rl] + p1[2][rl] + p1[3][rl] + l3b[1];
    float mm = fmaxf(l0, l1);
    float e0 = expf(l0 - mm), e1 = expf(l1 - mm);
    float inv = 1.f / (e0 + e1);
    out[(size_t)r*2]     = e0 * inv;
    out[(size_t)r*2 + 1] = e1 * inv;
  }
}

// =====================================================================
extern "C" void kernel_launch(void* const* d_in, const int* in_sizes, int n_in,
                              void* d_out, int out_size, void* d_ws, size_t ws_size,
                              hipStream_t stream)
{
  const float* x    = (const float*)d_in[0];
  const float* gc1w = (const float*)d_in[1];
  const float* gc2w = (const float*)d_in[2];
  const float* l1w  = (const float*)d_in[3];
  const float* l1b  = (const float*)d_in[4];
  const float* bn1g = (const float*)d_in[5];
  const float* bn1b = (const float*)d_in[6];
  const float* l2w  = (const float*)d_in[7];
  const float* l2b  = (const float*)d_in[8];
  const float* bn2g = (const float*)d_in[9];
  const float* bn2b = (const float*)d_in[10];
  const float* l3w  = (const float*)d_in[11];
  const float* l3b  = (const float*)d_in[12];
  float* out = (float*)d_out;

  // workspace layout (~34 MB)
  unsigned short* flatB = (unsigned short*)d_ws;                  // [4096][1824]
  unsigned short* wT1   = flatB + (size_t)Bn*D1P;                 // [512][1824]
  unsigned short* wT2   = wT1   + (size_t)C1*D1P;                 // [256][512]
  unsigned short* z1b   = wT2   + (size_t)C2*C1;                  // [4096][512]
  unsigned short* g1hi  = z1b   + (size_t)Bn*C1;                  // [32][224]
  unsigned short* g1lo  = g1hi  + (size_t)32*KT;
  float* Y1 = (float*)(g1lo + (size_t)32*KT);                     // [4096][512]
  float* Y2 = Y1 + (size_t)Bn*C1;                                 // [4096][256]
  float* a1 = Y2 + (size_t)Bn*C2;
  float* c1 = a1 + C1;
  float* a2 = c1 + C1;
  float* c2 = a2 + C2;

  hipLaunchKernelGGL(k_prep,   dim3(1024), dim3(256), 0, stream,
                     gc1w, l1w, l2w, g1hi, g1lo, wT1, wT2);
  hipLaunchKernelGGL(k_stage1, dim3(Bn),   dim3(256), 0, stream,
                     x, g1hi, g1lo, gc2w, flatB);
  hipLaunchKernelGGL(k_gemm_bt, dim3(Bn/64, C1/64), dim3(256), 0, stream,
                     flatB, wT1, l1b, Y1, D1P, D1P, C1, D1P/32);
  hipLaunchKernelGGL(k_bnstats, dim3(C1/16), dim3(256), 0, stream,
                     Y1, C1, bn1g, bn1b, a1, c1);
  hipLaunchKernelGGL(k_bnapply, dim3(2048), dim3(256), 0, stream,
                     Y1, a1, c1, z1b);
  hipLaunchKernelGGL(k_gemm_bt, dim3(Bn/64, C2/64), dim3(256), 0, stream,
                     z1b, wT2, l2b, Y2, C1, C1, C2, C1/32);
  hipLaunchKernelGGL(k_bnstats, dim3(C2/16), dim3(256), 0, stream,
                     Y2, C2, bn2g, bn2b, a2, c2);
  hipLaunchKernelGGL(k_final,  dim3(Bn/64), dim3(256), 0, stream,
                     Y2, a2, c2, l3w, l3b, out);
}

// Round 8
// 621.525 us; speedup vs baseline: 1.6169x; 1.6169x over previous
//
#include <hip/hip_runtime.h>

#define DEV __device__ __forceinline__

typedef __bf16 bf16x8 __attribute__((ext_vector_type(8)));
typedef float  f32x4  __attribute__((ext_vector_type(4)));

#define MFMA_BF16(A,B,C) __builtin_amdgcn_mfma_f32_16x16x32_bf16((A),(B),(C),0,0,0)

DEV unsigned short f2bf(float f) {
  unsigned int u = __builtin_bit_cast(unsigned int, f);
  u += 0x7fffu + ((u >> 16) & 1u);
  return (unsigned short)(u >> 16);
}
DEV float bf2f(unsigned short s) {
  unsigned int u = ((unsigned int)s) << 16;
  return __builtin_bit_cast(float, u);
}
DEV float sum8bf(int4 u) {
  float s = 0.f;
  s += bf2f((unsigned short)u.x) + bf2f((unsigned short)(((unsigned)u.x) >> 16));
  s += bf2f((unsigned short)u.y) + bf2f((unsigned short)(((unsigned)u.y) >> 16));
  s += bf2f((unsigned short)u.z) + bf2f((unsigned short)(((unsigned)u.z) >> 16));
  s += bf2f((unsigned short)u.w) + bf2f((unsigned short)(((unsigned)u.w) >> 16));
  return s;
}

// ---- problem sizes ----
constexpr int Bn  = 4096;
constexpr int Nr  = 90;
constexpr int Tt  = 195;
constexpr int Hh  = 20;
constexpr int NP  = 96;
constexpr int KT  = 224;
constexpr int XS  = 232;
constexpr int AS  = 104;
constexpr int D1P = 1824;
constexpr int C1  = 512;
constexpr int C2  = 256;

// =====================================================================
__global__ __launch_bounds__(256) void k_zero(float* __restrict__ p, int n) {
  int i = blockIdx.x*256 + threadIdx.x;
  if (i < n) p[i] = 0.f;
}

// =====================================================================
// prep0: gc1 hi/lo split (B-layout [h][t], zero-padded)
// =====================================================================
__global__ __launch_bounds__(256) void k_prep0(
    const float* __restrict__ gc1,
    unsigned short* __restrict__ g1hi, unsigned short* __restrict__ g1lo)
{
  for (int i = threadIdx.x; i < 32*KT; i += 256) {
    int h = i / KT, t = i - h*KT;
    float f = (h < Hh && t < Tt) ? gc1[t*Hh + h] : 0.f;
    unsigned short hi = f2bf(f);
    g1hi[i] = hi;
    g1lo[i] = f2bf(f - bf2f(hi));
  }
}

// =====================================================================
// prepT: LDS-tiled transpose W[K][C] fp32 -> out[C][KP] bf16 (K zero-padded)
// =====================================================================
__global__ __launch_bounds__(256) void k_prepT(
    const float* __restrict__ W, int K, int C, int KP,
    unsigned short* __restrict__ out)
{
  __shared__ float tile[32][33];
  const int kt = blockIdx.x, ct = blockIdx.y;
  const int cl = threadIdx.x & 31, kl = threadIdx.x >> 5;
  #pragma unroll
  for (int j = 0; j < 4; ++j) {
    int k = kt*32 + kl + j*8;
    int c = ct*32 + cl;
    tile[cl][kl + j*8] = (k < K) ? W[(size_t)k*C + c] : 0.f;
  }
  __syncthreads();
  const int ko = threadIdx.x & 31, co = threadIdx.x >> 5;
  #pragma unroll
  for (int j = 0; j < 4; ++j) {
    int c = co + j*8;
    out[(size_t)(ct*32 + c)*KP + kt*32 + ko] = f2bf(tile[c][ko]);
  }
}

// =====================================================================
// stage1: one block (512 thr, 8 waves) per sample.
// corr (split-bf16 MFMA) + GCN fused; waves specialized in phase 4.
// =====================================================================
__global__ __launch_bounds__(512) void k_stage1(
    const float* __restrict__ x,
    const unsigned short* __restrict__ g1hi,
    const unsigned short* __restrict__ g1lo,
    const float* __restrict__ gc2,
    unsigned short* __restrict__ flatB)
{
  __shared__ unsigned short xhi[NP][XS];
  __shared__ unsigned short xlo[NP][XS];
  __shared__ unsigned short adjh[NP][AS];
  __shared__ unsigned short adjl[NP][AS];
  __shared__ unsigned short xwbt[32][AS];
  __shared__ unsigned short hgbt[32][AS];
  __shared__ float shout[NP][21];
  __shared__ float smean[NP];
  __shared__ float sdinv[NP];
  __shared__ float scov[NP];

  const int tid = threadIdx.x;
  const int b   = blockIdx.x;
  const int w   = tid >> 6;
  const int l   = tid & 63;
  const int fm  = l & 15;
  const int fk  = (l >> 4) * 8;

  // ---- phase 1: issue all x loads up-front (float2: 8B-aligned for every b) ----
  const float* xb = x + (size_t)b * (Nr*Tt);
  float2 xr[18];
  #pragma unroll
  for (int it = 0; it < 18; ++it) {
    int v = tid + it*512;
    if (v < 8775) xr[it] = *(const float2*)(xb + 2*v);
  }

  // ---- phase 2: zero LDS (pads must be 0) ----
  {
    int4 z; z.x = z.y = z.z = z.w = 0;
    int4* p1 = (int4*)(&xhi[0][0]);
    int4* p2 = (int4*)(&xlo[0][0]);
    for (int i = tid; i < NP*XS/8; i += 512) { p1[i] = z; p2[i] = z; }
    int4* p3 = (int4*)(&adjh[0][0]);
    int4* p4 = (int4*)(&adjl[0][0]);
    for (int i = tid; i < NP*AS/8; i += 512) { p3[i] = z; p4[i] = z; }
    int4* p5 = (int4*)(&xwbt[0][0]);
    int4* p6 = (int4*)(&hgbt[0][0]);
    for (int i = tid; i < 32*AS/8; i += 512) { p5[i] = z; p6[i] = z; }
  }
  __syncthreads();

  // ---- phase 3: write x into LDS, hi/lo split ----
  #pragma unroll
  for (int it = 0; it < 18; ++it) {
    int v = tid + it*512;
    if (v < 8775) {
      int idx = 2*v;
      int r = idx / 195;
      int t = idx - r*195;
      float v0 = xr[it].x, v1 = xr[it].y;
      unsigned short h0 = f2bf(v0);
      xhi[r][t] = h0;
      xlo[r][t] = f2bf(v0 - bf2f(h0));
      int r1 = r, t1 = t + 1;
      if (t1 >= 195) { r1 = r + 1; t1 = 0; }
      unsigned short h1 = f2bf(v1);
      xhi[r1][t1] = h1;
      xlo[r1][t1] = f2bf(v1 - bf2f(h1));
    }
  }
  __syncthreads();

  // ---- phase 4 (wave-specialized): cov | x@gc1 | row-means ----
  f32x4 cacc[3][3];
  if (w < 4) {
    const int wr = w >> 1, wc = w & 1;
    #pragma unroll
    for (int i = 0; i < 3; ++i)
      #pragma unroll
      for (int j = 0; j < 3; ++j) cacc[i][j] = f32x4{0.f,0.f,0.f,0.f};
    for (int ks = 0; ks < 7; ++ks) {
      const int k0 = ks*32 + fk;
      bf16x8 ah[3], al[3], bh[3], bl[3];
      #pragma unroll
      for (int t2 = 0; t2 < 3; ++t2) {
        ah[t2] = *(const bf16x8*)(&xhi[wr*48 + t2*16 + fm][k0]);
        al[t2] = *(const bf16x8*)(&xlo[wr*48 + t2*16 + fm][k0]);
        bh[t2] = *(const bf16x8*)(&xhi[wc*48 + t2*16 + fm][k0]);
        bl[t2] = *(const bf16x8*)(&xlo[wc*48 + t2*16 + fm][k0]);
      }
      #pragma unroll
      for (int ti = 0; ti < 3; ++ti)
        #pragma unroll
        for (int tj = 0; tj < 3; ++tj) {
          cacc[ti][tj] = MFMA_BF16(ah[ti], bh[tj], cacc[ti][tj]);
          cacc[ti][tj] = MFMA_BF16(al[ti], bh[tj], cacc[ti][tj]);
          cacc[ti][tj] = MFMA_BF16(ah[ti], bl[tj], cacc[ti][tj]);
        }
    }
    if (wr == wc) {
      #pragma unroll
      for (int t2 = 0; t2 < 3; ++t2)
        #pragma unroll
        for (int reg = 0; reg < 4; ++reg) {
          int rloc = (l >> 4)*4 + reg;
          if (rloc == fm) scov[wr*48 + t2*16 + rloc] = cacc[t2][t2][reg];
        }
    }
  } else if (w < 6) {
    // xw = x @ gc1, write transposed bf16 xwbt[h][m]
    for (int mt = w - 4; mt < 6; mt += 2) {
      f32x4 xacc[2];
      xacc[0] = f32x4{0.f,0.f,0.f,0.f};
      xacc[1] = f32x4{0.f,0.f,0.f,0.f};
      for (int ks = 0; ks < 7; ++ks) {
        const int k0 = ks*32 + fk;
        bf16x8 ah = *(const bf16x8*)(&xhi[mt*16 + fm][k0]);
        bf16x8 al = *(const bf16x8*)(&xlo[mt*16 + fm][k0]);
        #pragma unroll
        for (int nt = 0; nt < 2; ++nt) {
          bf16x8 bh = *(const bf16x8*)(g1hi + (size_t)(nt*16 + fm)*KT + k0);
          bf16x8 bl = *(const bf16x8*)(g1lo + (size_t)(nt*16 + fm)*KT + k0);
          xacc[nt] = MFMA_BF16(ah, bh, xacc[nt]);
          xacc[nt] = MFMA_BF16(al, bh, xacc[nt]);
          xacc[nt] = MFMA_BF16(ah, bl, xacc[nt]);
        }
      }
      #pragma unroll
      for (int nt = 0; nt < 2; ++nt) {
        int hcol = nt*16 + fm;
        if (hcol < Hh) {
          #pragma unroll
          for (int reg = 0; reg < 4; ++reg) {
            int rr = mt*16 + (l>>4)*4 + reg;
            if (rr < Nr) xwbt[hcol][rr] = f2bf(xacc[nt][reg]);
          }
        }
      }
    }
  } else {
    // row means
    int r = tid - 384;
    if (r < Nr) {
      const int4* ph = (const int4*)(&xhi[r][0]);
      const int4* pl = (const int4*)(&xlo[r][0]);
      float s = 0.f;
      for (int q = 0; q < 28; ++q) { s += sum8bf(ph[q]); s += sum8bf(pl[q]); }
      smean[r] = s * (1.f/195.f);
    }
  }
  __syncthreads();

  if (tid < Nr) {
    float m = smean[tid];
    sdinv[tid] = rsqrtf(fmaxf(scov[tid] - 195.f*m*m, 1e-20f));
  }
  __syncthreads();

  // ---- corr -> adj bf16 hi/lo ----
  if (w < 4) {
    const int wr = w >> 1, wc = w & 1;
    #pragma unroll
    for (int ti = 0; ti < 3; ++ti) {
      #pragma unroll
      for (int tj = 0; tj < 3; ++tj) {
        int ccol = wc*48 + tj*16 + fm;
        if (ccol < Nr) {
          float mc = smean[ccol], dc = sdinv[ccol];
          #pragma unroll
          for (int reg = 0; reg < 4; ++reg) {
            int rr = wr*48 + ti*16 + (l>>4)*4 + reg;
            if (rr < Nr) {
              float v = (cacc[ti][tj][reg] - 195.f*smean[rr]*mc) * (sdinv[rr]*dc);
              v = fminf(1.f, fmaxf(-1.f, v));
              unsigned short hi = f2bf(v);
              adjh[rr][ccol] = hi;
              adjl[rr][ccol] = f2bf(v - bf2f(hi));
            }
          }
        }
      }
    }
  }
  __syncthreads();

  // ---- h1 = adj @ xw -> shout fp32 ----
  for (int mt = w; mt < 6; mt += 8) {
    f32x4 dacc[2];
    dacc[0] = f32x4{0.f,0.f,0.f,0.f};
    dacc[1] = f32x4{0.f,0.f,0.f,0.f};
    #pragma unroll
    for (int ks = 0; ks < 3; ++ks) {
      const int k0 = ks*32 + fk;
      bf16x8 ah = *(const bf16x8*)(&adjh[mt*16 + fm][k0]);
      bf16x8 al = *(const bf16x8*)(&adjl[mt*16 + fm][k0]);
      #pragma unroll
      for (int nt = 0; nt < 2; ++nt) {
        bf16x8 bb = *(const bf16x8*)(&xwbt[nt*16 + fm][k0]);
        dacc[nt] = MFMA_BF16(ah, bb, dacc[nt]);
        dacc[nt] = MFMA_BF16(al, bb, dacc[nt]);
      }
    }
    #pragma unroll
    for (int nt = 0; nt < 2; ++nt) {
      int hcol = nt*16 + fm;
      if (hcol < Hh) {
        #pragma unroll
        for (int reg = 0; reg < 4; ++reg) {
          int rr = mt*16 + (l>>4)*4 + reg;
          if (rr < Nr) shout[rr][hcol] = dacc[nt][reg];
        }
      }
    }
  }
  __syncthreads();

  // ---- h1g = h1 @ gc2 (fp32, uniform scalar weight loads) ----
  {
    int n = tid & 127;
    int g = tid >> 7;          // 0..3, wave-uniform
    int h0 = g * 5;
    if (n < Nr) {
      float acc2[5] = {0.f,0.f,0.f,0.f,0.f};
      for (int k = 0; k < Hh; ++k) {
        float v = shout[n][k];
        #pragma unroll
        for (int j = 0; j < 5; ++j) acc2[j] += v * gc2[k*Hh + h0 + j];
      }
      #pragma unroll
      for (int j = 0; j < 5; ++j) hgbt[h0 + j][n] = f2bf(acc2[j]);
    }
  }
  __syncthreads();

  // ---- h2 = adj @ h1g -> shout ----
  for (int mt = w; mt < 6; mt += 8) {
    f32x4 facc[2];
    facc[0] = f32x4{0.f,0.f,0.f,0.f};
    facc[1] = f32x4{0.f,0.f,0.f,0.f};
    #pragma unroll
    for (int ks = 0; ks < 3; ++ks) {
      const int k0 = ks*32 + fk;
      bf16x8 ah = *(const bf16x8*)(&adjh[mt*16 + fm][k0]);
      bf16x8 al = *(const bf16x8*)(&adjl[mt*16 + fm][k0]);
      #pragma unroll
      for (int nt = 0; nt < 2; ++nt) {
        bf16x8 bb = *(const bf16x8*)(&hgbt[nt*16 + fm][k0]);
        facc[nt] = MFMA_BF16(ah, bb, facc[nt]);
        facc[nt] = MFMA_BF16(al, bb, facc[nt]);
      }
    }
    #pragma unroll
    for (int nt = 0; nt < 2; ++nt) {
      int hcol = nt*16 + fm;
      if (hcol < Hh) {
        #pragma unroll
        for (int reg = 0; reg < 4; ++reg) {
          int rr = mt*16 + (l>>4)*4 + reg;
          if (rr < Nr) shout[rr][hcol] = facc[nt][reg];
        }
      }
    }
  }
  __syncthreads();

  // ---- store flat row bf16 (padded 1824) ----
  {
    const size_t base = (size_t)b * D1P;
    for (int i = tid; i < D1P; i += 512) {
      unsigned short v = 0;
      if (i < 1800) {
        int r = i / Hh;
        int c = i - r*Hh;
        v = f2bf(shout[r][c]);
      }
      flatB[base + i] = v;
    }
  }
}

// =====================================================================
// GEMM + fused BN column-stats: C = A @ WT^T + bias; atomics for sum/sumsq
// =====================================================================
__global__ __launch_bounds__(256) void k_gemm_bt(
    const unsigned short* __restrict__ A,
    const unsigned short* __restrict__ WT,
    const float* __restrict__ bias,
    float* __restrict__ C,
    int lda, int ldw, int ldc, int ksteps,
    float* __restrict__ gs1, float* __restrict__ gs2)
{
  const int tid = threadIdx.x;
  const int w = tid >> 6, l = tid & 63;
  const int wr = w >> 1, wc = w & 1;
  const int fm = l & 15, fk = (l >> 4) * 8;
  const int m0 = blockIdx.x * 64;
  const int n0 = blockIdx.y * 64;

  const unsigned short* pa0 = A  + (size_t)(m0 + wr*32 + fm) * lda + fk;
  const unsigned short* pa1 = pa0 + (size_t)16 * lda;
  const unsigned short* pb0 = WT + (size_t)(n0 + wc*32 + fm) * ldw + fk;
  const unsigned short* pb1 = pb0 + (size_t)16 * ldw;

  f32x4 acc00 = f32x4{0.f,0.f,0.f,0.f};
  f32x4 acc01 = acc00, acc10 = acc00, acc11 = acc00;

  for (int ks = 0; ks < ksteps; ++ks) {
    const int o = ks * 32;
    bf16x8 a0 = *(const bf16x8*)(pa0 + o);
    bf16x8 a1 = *(const bf16x8*)(pa1 + o);
    bf16x8 b0 = *(const bf16x8*)(pb0 + o);
    bf16x8 b1 = *(const bf16x8*)(pb1 + o);
    acc00 = MFMA_BF16(a0, b0, acc00);
    acc01 = MFMA_BF16(a0, b1, acc01);
    acc10 = MFMA_BF16(a1, b0, acc10);
    acc11 = MFMA_BF16(a1, b1, acc11);
  }

  const int rb = m0 + wr*32 + (l >> 4)*4;
  const int cb = n0 + wc*32 + fm;
  const float bv0 = bias[cb];
  const float bv1 = bias[cb + 16];
  float s10 = 0.f, s20 = 0.f, s11 = 0.f, s21 = 0.f;
  #pragma unroll
  for (int reg = 0; reg < 4; ++reg) {
    float y00 = acc00[reg] + bv0;
    float y01 = acc01[reg] + bv1;
    float y10 = acc10[reg] + bv0;
    float y11 = acc11[reg] + bv1;
    C[(size_t)(rb + reg)*ldc + cb]        = y00;
    C[(size_t)(rb + reg)*ldc + cb + 16]   = y01;
    C[(size_t)(rb + 16 + reg)*ldc + cb]   = y10;
    C[(size_t)(rb + 16 + reg)*ldc + cb+16]= y11;
    s10 += y00 + y10;  s20 += y00*y00 + y10*y10;
    s11 += y01 + y11;  s21 += y01*y01 + y11*y11;
  }
  s10 += __shfl_xor(s10, 16); s10 += __shfl_xor(s10, 32);
  s20 += __shfl_xor(s20, 16); s20 += __shfl_xor(s20, 32);
  s11 += __shfl_xor(s11, 16); s11 += __shfl_xor(s11, 32);
  s21 += __shfl_xor(s21, 16); s21 += __shfl_xor(s21, 32);
  if (l < 16) {
    atomicAdd(&gs1[cb], s10);
    atomicAdd(&gs2[cb], s20);
    atomicAdd(&gs1[cb + 16], s11);
    atomicAdd(&gs2[cb + 16], s21);
  }
}

// =====================================================================
// bnfin: a = gamma*rsqrt(var+eps), c = beta - a*mean
// =====================================================================
__global__ __launch_bounds__(512) void k_bnfin(
    const float* __restrict__ s1, const float* __restrict__ s2,
    const float* __restrict__ g, const float* __restrict__ bt,
    float* __restrict__ a, float* __restrict__ c, int C)
{
  int i = threadIdx.x;
  if (i < C) {
    float m   = s1[i] * (1.f/Bn);
    float var = fmaxf(s2[i] * (1.f/Bn) - m*m, 0.f);
    float av  = g[i] * rsqrtf(var + 1e-5f);
    a[i] = av;
    c[i] = bt[i] - av*m;
  }
}

// =====================================================================
// bnapply: Z = bf16(a*Y + c), vectorized
// =====================================================================
__global__ __launch_bounds__(256) void k_bnapply(
    const float* __restrict__ Y, const float* __restrict__ a,
    const float* __restrict__ cc, unsigned short* __restrict__ Z)
{
  int i4 = blockIdx.x*256 + threadIdx.x;
  if (i4 < Bn*C1/4) {
    int col = (i4*4) & (C1-1);
    float4 y  = *(const float4*)(Y + (size_t)i4*4);
    float4 av = *(const float4*)(a + col);
    float4 cv = *(const float4*)(cc + col);
    ushort4 o;
    o.x = f2bf(av.x*y.x + cv.x);
    o.y = f2bf(av.y*y.y + cv.y);
    o.z = f2bf(av.z*y.z + cv.z);
    o.w = f2bf(av.w*y.w + cv.w);
    *(ushort4*)(Z + (size_t)i4*4) = o;
  }
}

// =====================================================================
// final: logits = (a2*Y2+c2) @ l3_w + l3_b, softmax; per-wave rows,
// coalesced float4 loads + shfl-xor reduce
// =====================================================================
__global__ __launch_bounds__(256) void k_final(
    const float* __restrict__ Y2,
    const float* __restrict__ a2, const float* __restrict__ c2,
    const float* __restrict__ l3w, const float* __restrict__ l3b,
    float* __restrict__ out)
{
  const int w = threadIdx.x >> 6, l = threadIdx.x & 63;
  const int c = l * 4;
  float4 av = *(const float4*)(a2 + c);
  float4 cv = *(const float4*)(c2 + c);
  float4 wa = *(const float4*)(l3w + 2*c);      // w0[c],w1[c],w0[c+1],w1[c+1]
  float4 wb = *(const float4*)(l3w + 2*c + 4);  // w0[c+2],w1[c+2],w0[c+3],w1[c+3]
  const float b0 = l3b[0], b1 = l3b[1];
  const int row0 = blockIdx.x*64 + w*16;
  for (int rr = 0; rr < 16; ++rr) {
    int r = row0 + rr;
    float4 y = *(const float4*)(Y2 + (size_t)r*C2 + c);
    float z0 = av.x*y.x + cv.x, z1 = av.y*y.y + cv.y;
    float z2 = av.z*y.z + cv.z, z3 = av.w*y.w + cv.w;
    float s0 = z0*wa.x + z1*wa.z + z2*wb.x + z3*wb.z;
    float s1 = z0*wa.y + z1*wa.w + z2*wb.y + z3*wb.w;
    #pragma unroll
    for (int m = 1; m < 64; m <<= 1) {
      s0 += __shfl_xor(s0, m, 64);
      s1 += __shfl_xor(s1, m, 64);
    }
    if (l == 0) {
      float l0 = s0 + b0, l1 = s1 + b1;
      float mm = fmaxf(l0, l1);
      float e0 = expf(l0 - mm), e1 = expf(l1 - mm);
      float inv = 1.f / (e0 + e1);
      *(float2*)(out + (size_t)r*2) = float2{e0*inv, e1*inv};
    }
  }
}

// =====================================================================
extern "C" void kernel_launch(void* const* d_in, const int* in_sizes, int n_in,
                              void* d_out, int out_size, void* d_ws, size_t ws_size,
                              hipStream_t stream)
{
  const float* x    = (const float*)d_in[0];
  const float* gc1w = (const float*)d_in[1];
  const float* gc2w = (const float*)d_in[2];
  const float* l1w  = (const float*)d_in[3];
  const float* l1b  = (const float*)d_in[4];
  const float* bn1g = (const float*)d_in[5];
  const float* bn1b = (const float*)d_in[6];
  const float* l2w  = (const float*)d_in[7];
  const float* l2b  = (const float*)d_in[8];
  const float* bn2g = (const float*)d_in[9];
  const float* bn2b = (const float*)d_in[10];
  const float* l3w  = (const float*)d_in[11];
  const float* l3b  = (const float*)d_in[12];
  float* out = (float*)d_out;

  // workspace layout
  unsigned short* flatB = (unsigned short*)d_ws;                  // [4096][1824]
  unsigned short* wT1   = flatB + (size_t)Bn*D1P;                 // [512][1824]
  unsigned short* wT2   = wT1   + (size_t)C1*D1P;                 // [256][512]
  unsigned short* z1b   = wT2   + (size_t)C2*C1;                  // [4096][512]
  unsigned short* g1hi  = z1b   + (size_t)Bn*C1;                  // [32][224]
  unsigned short* g1lo  = g1hi  + (size_t)32*KT;
  float* Y1 = (float*)(g1lo + (size_t)32*KT);                     // [4096][512]
  float* Y2 = Y1 + (size_t)Bn*C1;                                 // [4096][256]
  float* a1 = Y2 + (size_t)Bn*C2;
  float* c1 = a1 + C1;
  float* a2 = c1 + C1;
  float* c2 = a2 + C2;
  float* s1a = c2 + C2;        // [512]
  float* s2a = s1a + C1;       // [512]
  float* s1b = s2a + C1;       // [256]
  float* s2b = s1b + C2;       // [256]

  hipLaunchKernelGGL(k_zero, dim3(6), dim3(256), 0, stream,
                     s1a, 2*C1 + 2*C2);
  hipLaunchKernelGGL(k_prep0, dim3(1), dim3(256), 0, stream, gc1w, g1hi, g1lo);
  hipLaunchKernelGGL(k_prepT, dim3(D1P/32, C1/32), dim3(256), 0, stream,
                     l1w, 1800, C1, D1P, wT1);
  hipLaunchKernelGGL(k_prepT, dim3(C1/32, C2/32), dim3(256), 0, stream,
                     l2w, C1, C2, C1, wT2);
  hipLaunchKernelGGL(k_stage1, dim3(Bn), dim3(512), 0, stream,
                     x, g1hi, g1lo, gc2w, flatB);
  hipLaunchKernelGGL(k_gemm_bt, dim3(Bn/64, C1/64), dim3(256), 0, stream,
                     flatB, wT1, l1b, Y1, D1P, D1P, C1, D1P/32, s1a, s2a);
  hipLaunchKernelGGL(k_bnfin, dim3(1), dim3(512), 0, stream,
                     s1a, s2a, bn1g, bn1b, a1, c1, C1);
  hipLaunchKernelGGL(k_bnapply, dim3(Bn*C1/4/256), dim3(256), 0, stream,
                     Y1, a1, c1, z1b);
  hipLaunchKernelGGL(k_gemm_bt, dim3(Bn/64, C2/64), dim3(256), 0, stream,
                     z1b, wT2, l2b, Y2, C1, C1, C2, C1/32, s1b, s2b);
  hipLaunchKernelGGL(k_bnfin, dim3(1), dim3(512), 0, stream,
                     s1b, s2b, bn2g, bn2b, a2, c2, C2);
  hipLaunchKernelGGL(k_final, dim3(Bn/64), dim3(256), 0, stream,
                     Y2, a2, c2, l3w, l3b, out);
}